// Round 1
// baseline (13663.004 us; speedup 1.0000x reference)
//
#include <hip/hip_runtime.h>

// ---------------------------------------------------------------------------
// MiniBatchEdgePropPlus — fp32 baseline (round 0)
// H = 256 hidden, wave=64, block=256 threads everywhere.
// ---------------------------------------------------------------------------

__device__ __forceinline__ float sigmoid_f(float x){
  x = fminf(fmaxf(x, -30.f), 30.f);
  return __fdividef(1.f, 1.f + __expf(-x));
}
__device__ __forceinline__ float tanh_f(float x){
  x = fminf(fmaxf(x, -15.f), 15.f);
  float e = __expf(-2.f * x);
  return __fdividef(1.f - e, 1.f + e);
}

// Block-wide LN stats for R rows of a [R x 256] LDS buffer.
// Each of the 4 waves reduces R/4 rows. Caller syncs before & after.
template<int R>
__device__ __forceinline__ void ln_stats_rows(const float* __restrict__ O,
                                              float* __restrict__ mean_s,
                                              float* __restrict__ rstd_s){
  const int tid  = threadIdx.x;
  const int wave = tid >> 6, lane = tid & 63;
  constexpr int RW = R / 4;
  #pragma unroll
  for (int rr = 0; rr < RW; rr++){
    const int r = wave * RW + rr;
    float s = 0.f, q = 0.f;
    #pragma unroll
    for (int i = lane; i < 256; i += 64){ float v = O[r*256 + i]; s += v; q += v*v; }
    #pragma unroll
    for (int off = 32; off; off >>= 1){ s += __shfl_down(s, off); q += __shfl_down(q, off); }
    if (lane == 0){
      float m   = s * (1.f/256.f);
      float var = q * (1.f/256.f) - m*m;
      mean_s[r] = m;
      rstd_s[r] = rsqrtf(fmaxf(var, 0.f) + 1e-5f);
    }
  }
}

// ---------------------------------------------------------------------------
// Fused per-edge kernel: GRU(8 steps) -> mean -> phi SLNN on [nodef[src]|emb]
// -> msg = relu(nb - hist[src]) -> atomicAdd into delta[dst].
// DIN: GRU input dim (64 / 256). NFD: node-feature dim (128 / 256).
// ---------------------------------------------------------------------------
template<int DIN, int NFD>
__global__ __launch_bounds__(256, 2)
void gru_nb_kernel(int E,
    const float* __restrict__ x,      // [E, 8, DIN]
    const float* __restrict__ nodef,  // [*, NFD]
    const int*   __restrict__ src,
    const int*   __restrict__ dst,
    const float* __restrict__ hist,   // [*, 256]
    const float* __restrict__ Wih,    // [768, DIN]
    const float* __restrict__ Whh,    // [768, 256]
    const float* __restrict__ bih,
    const float* __restrict__ bhh,
    const float* __restrict__ phiW,   // [256, NFD+256]
    const float* __restrict__ phib,
    const float* __restrict__ phig,
    const float* __restrict__ phibeta,
    float* __restrict__ delta)        // [*, 256], pre-zeroed, atomic
{
  constexpr int TM = 32;
  constexpr int XW = (DIN > NFD) ? DIN : NFD;
  __shared__ float hl[TM*256];
  __shared__ float xl[TM*XW];
  __shared__ float mean_s[TM], rstd_s[TM];
  __shared__ int   srcs[TM], dsts[TM];

  const int tid = threadIdx.x;
  const int e0  = blockIdx.x * TM;
  const int c   = tid;

  for (int i = tid; i < TM*256; i += 256) hl[i] = 0.f;
  if (tid < TM){
    int e = e0 + tid;
    srcs[tid] = (e < E) ? src[e] : 0;
    dsts[tid] = (e < E) ? dst[e] : 0;
  }

  const float* Wr = Whh + (size_t)c*256;
  const float* Wz = Whh + (size_t)(256+c)*256;
  const float* Wn = Whh + (size_t)(512+c)*256;
  const float* Ur = Wih + (size_t)c*DIN;
  const float* Uz = Wih + (size_t)(256+c)*DIN;
  const float* Un = Wih + (size_t)(512+c)*DIN;
  const float brc  = bih[c]     + bhh[c];
  const float bzc  = bih[256+c] + bhh[256+c];
  const float bnic = bih[512+c];
  const float bnhc = bhh[512+c];

  float hsum[TM];
  #pragma unroll
  for (int e = 0; e < TM; e++) hsum[e] = 0.f;

  for (int t = 0; t < 8; t++){
    __syncthreads();   // protects hl (prev writes) and xl (prev reads)
    for (int i = tid; i < TM*DIN; i += 256){
      int e = i / DIN, k = i - e*DIN;
      int ge = e0 + e;
      xl[i] = (ge < E) ? x[(size_t)ge*(8*DIN) + t*DIN + k] : 0.f;
    }
    __syncthreads();

    float accr[TM], accz[TM], accni[TM], accnh[TM];
    #pragma unroll
    for (int e = 0; e < TM; e++){ accr[e]=0.f; accz[e]=0.f; accni[e]=0.f; accnh[e]=0.f; }

    if (t > 0){  // h == 0 at t == 0
      #pragma unroll 1
      for (int k = 0; k < 256; k += 4){
        float4 wr = *(const float4*)(Wr + k);
        float4 wz = *(const float4*)(Wz + k);
        float4 wn = *(const float4*)(Wn + k);
        #pragma unroll
        for (int e = 0; e < TM; e++){
          float4 hv = *(const float4*)(hl + e*256 + k);
          accr[e]  += wr.x*hv.x + wr.y*hv.y + wr.z*hv.z + wr.w*hv.w;
          accz[e]  += wz.x*hv.x + wz.y*hv.y + wz.z*hv.z + wz.w*hv.w;
          accnh[e] += wn.x*hv.x + wn.y*hv.y + wn.z*hv.z + wn.w*hv.w;
        }
      }
    }
    #pragma unroll 1
    for (int k = 0; k < DIN; k += 4){
      float4 ur = *(const float4*)(Ur + k);
      float4 uz = *(const float4*)(Uz + k);
      float4 un = *(const float4*)(Un + k);
      #pragma unroll
      for (int e = 0; e < TM; e++){
        float4 xv = *(const float4*)(xl + e*DIN + k);
        accr[e]  += ur.x*xv.x + ur.y*xv.y + ur.z*xv.z + ur.w*xv.w;
        accz[e]  += uz.x*xv.x + uz.y*xv.y + uz.z*xv.z + uz.w*xv.w;
        accni[e] += un.x*xv.x + un.y*xv.y + un.z*xv.z + un.w*xv.w;
      }
    }
    __syncthreads();   // all GEMM reads of hl done before column updates
    #pragma unroll
    for (int e = 0; e < TM; e++){
      float r    = sigmoid_f(accr[e] + brc);
      float z    = sigmoid_f(accz[e] + bzc);
      float n    = tanh_f(accni[e] + bnic + r*(accnh[e] + bnhc));
      float hold = hl[e*256 + c];
      float hnew = (1.f - z)*n + z*hold;
      hl[e*256 + c] = hnew;
      hsum[e] += hnew;
    }
  }

  __syncthreads();
  #pragma unroll
  for (int e = 0; e < TM; e++) hl[e*256 + c] = hsum[e] * 0.125f;   // emb = mean
  for (int i = tid; i < TM*NFD; i += 256){
    int e = i / NFD, k = i - e*NFD;
    xl[e*NFD + k] = nodef[(size_t)srcs[e]*NFD + k];
  }
  __syncthreads();

  // phi GEMM over concat([nodef, emb]) : K = NFD + 256
  const float* Wp = phiW + (size_t)c*(NFD+256);
  float acc2[TM];
  const float pb = phib[c];
  #pragma unroll
  for (int e = 0; e < TM; e++) acc2[e] = pb;
  #pragma unroll 1
  for (int k = 0; k < NFD; k += 4){
    float4 w = *(const float4*)(Wp + k);
    #pragma unroll
    for (int e = 0; e < TM; e++){
      float4 xv = *(const float4*)(xl + e*NFD + k);
      acc2[e] += w.x*xv.x + w.y*xv.y + w.z*xv.z + w.w*xv.w;
    }
  }
  #pragma unroll 1
  for (int k = 0; k < 256; k += 4){
    float4 w = *(const float4*)(Wp + NFD + k);
    #pragma unroll
    for (int e = 0; e < TM; e++){
      float4 hv = *(const float4*)(hl + e*256 + k);
      acc2[e] += w.x*hv.x + w.y*hv.y + w.z*hv.z + w.w*hv.w;
    }
  }

  __syncthreads();
  #pragma unroll
  for (int e = 0; e < TM; e++) hl[e*256 + c] = acc2[e];
  __syncthreads();
  ln_stats_rows<TM>(hl, mean_s, rstd_s);
  __syncthreads();

  const float gc = phig[c], bc = phibeta[c];
  #pragma unroll
  for (int e = 0; e < TM; e++){
    if (e0 + e < E){
      float y = (acc2[e] - mean_s[e]) * rstd_s[e] * gc + bc;
      y = fmaxf(y, 0.f);                                    // nb
      float m = y - hist[(size_t)srcs[e]*256 + c];          // nb - hist[src]
      if (m > 0.f) atomicAdd(delta + (size_t)dsts[e]*256 + c, m);
    }
  }
}

// ---------------------------------------------------------------------------
// self-SLNN: out = relu(LN(feat[nid] @ W[:, WS-K:].T + b)); optional
// out2 = out - hist[nid] (for self_delta_h1).
// ---------------------------------------------------------------------------
template<int K, int WS>
__global__ __launch_bounds__(256)
void self_slnn_kernel(int N,
    const float* __restrict__ feat,
    const int*   __restrict__ nid,
    const float* __restrict__ W,
    const float* __restrict__ b,
    const float* __restrict__ g,
    const float* __restrict__ beta,
    const float* __restrict__ hist,
    float* __restrict__ out,
    float* __restrict__ out2)
{
  constexpr int R = 8;
  __shared__ float X[R*K];
  __shared__ float O[R*256];
  __shared__ float mean_s[R], rstd_s[R];
  __shared__ int   nids[R];
  const int tid = threadIdx.x;
  const int n0  = blockIdx.x * R;
  if (tid < R) nids[tid] = (n0 + tid < N) ? nid[n0 + tid] : 0;
  __syncthreads();
  for (int i = tid; i < R*K; i += 256){
    int r = i / K, k = i - r*K;
    X[i] = feat[(size_t)nids[r]*K + k];
  }
  __syncthreads();
  const int c = tid;
  const float* Wc = W + (size_t)c*WS + (WS - K);
  float acc[R];
  const float bc0 = b[c];
  #pragma unroll
  for (int r = 0; r < R; r++) acc[r] = bc0;
  #pragma unroll 1
  for (int k = 0; k < K; k += 4){
    float4 w = *(const float4*)(Wc + k);
    #pragma unroll
    for (int r = 0; r < R; r++){
      float4 xv = *(const float4*)(X + r*K + k);
      acc[r] += w.x*xv.x + w.y*xv.y + w.z*xv.z + w.w*xv.w;
    }
  }
  #pragma unroll
  for (int r = 0; r < R; r++) O[r*256 + c] = acc[r];
  __syncthreads();
  ln_stats_rows<R>(O, mean_s, rstd_s);
  __syncthreads();
  const float gc = g[c], bc = beta[c];
  #pragma unroll
  for (int r = 0; r < R; r++){
    int n = n0 + r;
    if (n < N){
      float y = fmaxf((acc[r] - mean_s[r]) * rstd_s[r] * gc + bc, 0.f);
      out[(size_t)n*256 + c] = y;
      if (out2) out2[(size_t)n*256 + c] = y - hist[(size_t)nids[r]*256 + c];
    }
  }
}

// ---------------------------------------------------------------------------
// compose-SLNN: X = [ (delta - selfA)*subg (+ agg*normv) | selfB ]  (K=512)
// out = relu(LN(X @ W.T + b))
// ---------------------------------------------------------------------------
__global__ __launch_bounds__(256)
void compose_slnn_kernel(int N,
    const float* __restrict__ delta,
    const float* __restrict__ selfA,
    const float* __restrict__ selfB,
    const float* __restrict__ subg,
    const float* __restrict__ agg,
    const float* __restrict__ normv,
    const float* __restrict__ W,     // [256, 512]
    const float* __restrict__ b,
    const float* __restrict__ g,
    const float* __restrict__ beta,
    float* __restrict__ out)
{
  constexpr int R = 8;
  __shared__ float X[R*512];
  __shared__ float O[R*256];
  __shared__ float mean_s[R], rstd_s[R];
  const int tid = threadIdx.x;
  const int n0  = blockIdx.x * R;
  for (int i = tid; i < R*512; i += 256){
    int r = i >> 9, k = i & 511;
    int n = n0 + r;
    float v = 0.f;
    if (n < N){
      if (k < 256){
        v = (delta[(size_t)n*256 + k] - selfA[(size_t)n*256 + k]) * subg[n];
        if (agg) v += agg[(size_t)n*256 + k] * normv[n];
      } else {
        v = selfB[(size_t)n*256 + (k - 256)];
      }
    }
    X[i] = v;
  }
  __syncthreads();
  const int c = tid;
  const float* Wc = W + (size_t)c*512;
  float acc[R];
  const float bc0 = b[c];
  #pragma unroll
  for (int r = 0; r < R; r++) acc[r] = bc0;
  #pragma unroll 1
  for (int k = 0; k < 512; k += 4){
    float4 w = *(const float4*)(Wc + k);
    #pragma unroll
    for (int r = 0; r < R; r++){
      float4 xv = *(const float4*)(X + r*512 + k);
      acc[r] += w.x*xv.x + w.y*xv.y + w.z*xv.z + w.w*xv.w;
    }
  }
  #pragma unroll
  for (int r = 0; r < R; r++) O[r*256 + c] = acc[r];
  __syncthreads();
  ln_stats_rows<R>(O, mean_s, rstd_s);
  __syncthreads();
  const float gc = g[c], bc = beta[c];
  #pragma unroll
  for (int r = 0; r < R; r++){
    int n = n0 + r;
    if (n < N)
      out[(size_t)n*256 + c] = fmaxf((acc[r] - mean_s[r]) * rstd_s[r] * gc + bc, 0.f);
  }
}

// ---------------------------------------------------------------------------
// readout: logit = (h2 @ fc1.T + b1) @ fc2.T + b2   (no activation between)
// ---------------------------------------------------------------------------
__global__ __launch_bounds__(256)
void readout_kernel(int N,
    const float* __restrict__ h2,
    const float* __restrict__ W1,  // [512, 256]
    const float* __restrict__ b1,
    const float* __restrict__ W2,  // [16, 512]
    const float* __restrict__ b2,
    float* __restrict__ out)
{
  constexpr int R = 8;
  __shared__ float X[R*256];
  __shared__ float T[R*512];
  const int tid = threadIdx.x;
  const int n0  = blockIdx.x * R;
  for (int i = tid; i < R*256; i += 256){
    int r = i >> 8, k = i & 255;
    int n = n0 + r;
    X[i] = (n < N) ? h2[(size_t)n*256 + k] : 0.f;
  }
  __syncthreads();
  const int c = tid;
  const float* Wa = W1 + (size_t)c*256;
  const float* Wb = W1 + (size_t)(c+256)*256;
  float acca[R], accb[R];
  const float ba = b1[c], bb = b1[c+256];
  #pragma unroll
  for (int r = 0; r < R; r++){ acca[r] = ba; accb[r] = bb; }
  #pragma unroll 1
  for (int k = 0; k < 256; k += 4){
    float4 wa = *(const float4*)(Wa + k);
    float4 wb = *(const float4*)(Wb + k);
    #pragma unroll
    for (int r = 0; r < R; r++){
      float4 xv = *(const float4*)(X + r*256 + k);
      acca[r] += wa.x*xv.x + wa.y*xv.y + wa.z*xv.z + wa.w*xv.w;
      accb[r] += wb.x*xv.x + wb.y*xv.y + wb.z*xv.z + wb.w*xv.w;
    }
  }
  #pragma unroll
  for (int r = 0; r < R; r++){ T[r*512 + c] = acca[r]; T[r*512 + 256 + c] = accb[r]; }
  __syncthreads();
  if (tid < R*16){
    int r = tid >> 4, o = tid & 15;
    int n = n0 + r;
    if (n < N){
      float s = b2[o];
      const float* w  = W2 + (size_t)o*512;
      const float* tr = T + r*512;
      #pragma unroll 4
      for (int k = 0; k < 512; k++) s += tr[k]*w[k];
      out[(size_t)n*16 + o] = s;
    }
  }
}

// ---------------------------------------------------------------------------
extern "C" void kernel_launch(void* const* d_in, const int* in_sizes, int n_in,
                              void* d_out, int out_size, void* d_ws, size_t ws_size,
                              hipStream_t stream) {
  const float* nf     = (const float*)d_in[0];
  const float* x0     = (const float*)d_in[1];
  const float* x1     = (const float*)d_in[2];
  const float* hist0  = (const float*)d_in[3];
  const float* hist1  = (const float*)d_in[4];
  const float* aggh1  = (const float*)d_in[5];
  const float* subg1  = (const float*)d_in[6];
  const float* subg2  = (const float*)d_in[7];
  const float* norm2  = (const float*)d_in[8];
  const int*   src0   = (const int*)d_in[9];
  const int*   dst0   = (const int*)d_in[10];
  const int*   src1   = (const int*)d_in[11];
  const int*   dst1   = (const int*)d_in[12];
  const int*   nid0   = (const int*)d_in[13];
  const int*   nid1   = (const int*)d_in[14];
  const float* g0Wih  = (const float*)d_in[15];
  const float* g0Whh  = (const float*)d_in[16];
  const float* g0bih  = (const float*)d_in[17];
  const float* g0bhh  = (const float*)d_in[18];
  const float* g1Wih  = (const float*)d_in[19];
  const float* g1Whh  = (const float*)d_in[20];
  const float* g1bih  = (const float*)d_in[21];
  const float* g1bhh  = (const float*)d_in[22];
  const float* phi0W  = (const float*)d_in[23];
  const float* phi0b  = (const float*)d_in[24];
  const float* phi0g  = (const float*)d_in[25];
  const float* phi0be = (const float*)d_in[26];
  const float* phi1W  = (const float*)d_in[27];
  const float* phi1b  = (const float*)d_in[28];
  const float* phi1g  = (const float*)d_in[29];
  const float* phi1be = (const float*)d_in[30];
  const float* nu0W   = (const float*)d_in[31];
  const float* nu0b   = (const float*)d_in[32];
  const float* nu0g   = (const float*)d_in[33];
  const float* nu0be  = (const float*)d_in[34];
  const float* nu1W   = (const float*)d_in[35];
  const float* nu1b   = (const float*)d_in[36];
  const float* nu1g   = (const float*)d_in[37];
  const float* nu1be  = (const float*)d_in[38];
  const float* fc1W   = (const float*)d_in[39];
  const float* fc1b   = (const float*)d_in[40];
  const float* fc2W   = (const float*)d_in[41];
  const float* fc2b   = (const float*)d_in[42];

  const int E0 = in_sizes[9];
  const int E1 = in_sizes[11];
  const int N1 = in_sizes[13];
  const int N2 = in_sizes[14];

  float* ws     = (float*)d_ws;
  float* delta0 = ws;                              // [N1,256]
  float* selfh0 = delta0 + (size_t)N1*256;         // [N1,256]
  float* h1p    = selfh0 + (size_t)N1*256;         // [N1,256]
  float* delta1 = h1p    + (size_t)N1*256;         // [N2,256]
  float* selfh1 = delta1 + (size_t)N2*256;         // [N2,256]
  float* selfd1 = selfh1 + (size_t)N2*256;         // [N2,256]
  float* h2p    = selfd1 + (size_t)N2*256;         // [N2,256]

  hipMemsetAsync(delta0, 0, (size_t)N1*256*sizeof(float), stream);
  hipMemsetAsync(delta1, 0, (size_t)N2*256*sizeof(float), stream);

  const int gN1 = (N1 + 7) / 8;
  const int gN2 = (N2 + 7) / 8;

  // ---- layer 0 ----
  self_slnn_kernel<128, 384><<<gN1, 256, 0, stream>>>(
      N1, nf, nid0, phi0W, phi0b, phi0g, phi0be, nullptr, selfh0, nullptr);

  gru_nb_kernel<64, 128><<<(E0 + 31) / 32, 256, 0, stream>>>(
      E0, x0, nf, src0, dst0, hist0,
      g0Wih, g0Whh, g0bih, g0bhh,
      phi0W, phi0b, phi0g, phi0be, delta0);

  compose_slnn_kernel<<<gN1, 256, 0, stream>>>(
      N1, delta0, selfh0, selfh0, subg1, nullptr, nullptr,
      nu0W, nu0b, nu0g, nu0be, h1p);

  // ---- layer 1 ----
  self_slnn_kernel<256, 512><<<gN2, 256, 0, stream>>>(
      N2, h1p, nid1, phi1W, phi1b, phi1g, phi1be, hist1, selfh1, selfd1);

  gru_nb_kernel<256, 256><<<(E1 + 31) / 32, 256, 0, stream>>>(
      E1, x1, h1p, src1, dst1, hist1,
      g1Wih, g1Whh, g1bih, g1bhh,
      phi1W, phi1b, phi1g, phi1be, delta1);

  compose_slnn_kernel<<<gN2, 256, 0, stream>>>(
      N2, delta1, selfd1, selfh1, subg2, aggh1, norm2,
      nu1W, nu1b, nu1g, nu1be, h2p);

  // ---- readout ----
  readout_kernel<<<gN2, 256, 0, stream>>>(
      N2, h2p, fc1W, fc1b, fc2W, fc2b, (float*)d_out);

  (void)n_in; (void)out_size; (void)ws_size;
}

// Round 2
// 3262.568 us; speedup vs baseline: 4.1878x; 4.1878x over previous
//
#include <hip/hip_runtime.h>

typedef unsigned short u16;
typedef __attribute__((ext_vector_type(4))) float f32x4;
typedef __attribute__((ext_vector_type(8))) short bf16x8;
#define MFMA16(a,b,c) __builtin_amdgcn_mfma_f32_16x16x32_bf16((a),(b),(c),0,0,0)

__device__ __forceinline__ u16 f2bf(float f){
  unsigned int u = __float_as_uint(f);
  u += 0x7FFFu + ((u >> 16) & 1u);
  return (u16)(u >> 16);
}
__device__ __forceinline__ float bf2f(u16 h){
  return __uint_as_float(((unsigned int)h) << 16);
}
__device__ __forceinline__ float sigmoid_f(float x){
  x = fminf(fmaxf(x, -30.f), 30.f);
  return __fdividef(1.f, 1.f + __expf(-x));
}
__device__ __forceinline__ float tanh_f(float x){
  x = fminf(fmaxf(x, -15.f), 15.f);
  float e = __expf(-2.f * x);
  return __fdividef(1.f - e, 1.f + e);
}

// fp32 -> bf16 weight conversion (grid-stride)
__global__ void cvt_bf16_kernel(const float* __restrict__ in, u16* __restrict__ out, int n){
  int i = blockIdx.x * 256 + threadIdx.x;
  int stride = gridDim.x * 256;
  for (; i < n; i += stride) out[i] = f2bf(in[i]);
}

// Block-wide LN stats for R rows of a [R x 256] LDS buffer (stride 256).
template<int R>
__device__ __forceinline__ void ln_stats_rows(const float* __restrict__ O,
                                              float* __restrict__ mean_s,
                                              float* __restrict__ rstd_s){
  const int tid  = threadIdx.x;
  const int wave = tid >> 6, lane = tid & 63;
  constexpr int RW = R / 4;
  #pragma unroll
  for (int rr = 0; rr < RW; rr++){
    const int r = wave * RW + rr;
    float s = 0.f, q = 0.f;
    #pragma unroll
    for (int i = lane; i < 256; i += 64){ float v = O[r*256 + i]; s += v; q += v*v; }
    #pragma unroll
    for (int off = 32; off; off >>= 1){ s += __shfl_down(s, off); q += __shfl_down(q, off); }
    if (lane == 0){
      float m   = s * (1.f/256.f);
      float var = q * (1.f/256.f) - m*m;
      mean_s[r] = m;
      rstd_s[r] = rsqrtf(fmaxf(var, 0.f) + 1e-5f);
    }
  }
}

// ---------------------------------------------------------------------------
// MFMA-based fused per-edge kernel: GRU(8 steps, bf16 MFMA) -> mean ->
// phi SLNN on [nodef[src]|emb] -> msg = relu(nb - hist[src]) -> atomicAdd.
// TM=32 edges/block, 4 waves; wave w owns output cols [w*64, w*64+64).
// h kept as bf16 in double-buffered LDS; acc/gates fp32 in registers.
// ---------------------------------------------------------------------------
template<int DIN, int NFD>
__global__ __launch_bounds__(256, 2)
void gru_mfma_kernel(int E,
    const float* __restrict__ x,        // [E, 8, DIN] fp32
    const float* __restrict__ nodef,    // [*, NFD] fp32
    const int*   __restrict__ src,
    const int*   __restrict__ dst,
    const float* __restrict__ hist,     // [*, 256] fp32
    const u16*   __restrict__ Wih,      // [768, DIN] bf16
    const u16*   __restrict__ Whh,      // [768, 256] bf16
    const float* __restrict__ bih,
    const float* __restrict__ bhh,
    const u16*   __restrict__ phiW,     // [256, NFD+256] bf16
    const float* __restrict__ phib,
    const float* __restrict__ phig,
    const float* __restrict__ phibeta,
    float* __restrict__ delta)          // [*, 256] fp32, pre-zeroed
{
  constexpr int HP  = 264;                       // h row stride (+8 pad: 2-way banks)
  constexpr int XW  = (DIN > NFD) ? DIN : NFD;
  constexpr int XLP = XW + 8;
  constexpr int KP  = NFD + 256;                 // phi K

  __shared__ u16  hb[2 * 32 * HP];
  __shared__ u16  xl[32 * XLP];
  __shared__ float sums_s[4 * 32], sqs_s[4 * 32];
  __shared__ float mean_s[32], rstd_s[32];
  __shared__ int   srcs_s[32], dsts_s[32];

  const int tid  = threadIdx.x;
  const int wave = tid >> 6, lane = tid & 63;
  const int quad = lane >> 4, ln15 = lane & 15;
  const int cbase = wave * 64;
  const int e0   = blockIdx.x * 32;

  if (tid < 32){
    int e = e0 + tid;
    int ec = (e < E) ? e : (E - 1);
    srcs_s[tid] = src[ec];
    dsts_s[tid] = dst[ec];
  }

  int cnt[4];
  float brc[4], bzc[4], bnic[4], bnhc[4], pb[4], gg[4], gb[4];
  #pragma unroll
  for (int nt = 0; nt < 4; nt++){
    int c = cbase + nt*16 + ln15;
    cnt[nt]  = c;
    brc[nt]  = bih[c]       + bhh[c];
    bzc[nt]  = bih[256 + c] + bhh[256 + c];
    bnic[nt] = bih[512 + c];
    bnhc[nt] = bhh[512 + c];
    pb[nt]   = phib[c];
    gg[nt]   = phig[c];
    gb[nt]   = phibeta[c];
  }

  const int aoff = ln15 * HP  + quad * 8;   // A-frag base (elements) in h buffers
  const int xoff = ln15 * XLP + quad * 8;   // A-frag base in x buffer
  const int qoff = quad * 8;

  float hs[2][4][4];
  #pragma unroll
  for (int mt = 0; mt < 2; mt++)
    #pragma unroll
    for (int nt = 0; nt < 4; nt++)
      #pragma unroll
      for (int q = 0; q < 4; q++) hs[mt][nt][q] = 0.f;

  const f32x4 zero4 = {0.f, 0.f, 0.f, 0.f};

  for (int t = 0; t < 8; t++){
    __syncthreads();
    // stage x_t (fp32 -> bf16)
    {
      constexpr int R4 = DIN / 4;
      for (int i = tid; i < 32 * R4; i += 256){
        int e  = i / R4;
        int k4 = (i - e * R4) * 4;
        int ge = (e0 + e < E) ? (e0 + e) : (E - 1);
        const float4 v = *(const float4*)(x + (size_t)ge * (8 * DIN) + (size_t)t * DIN + k4);
        ushort4 u;
        u.x = f2bf(v.x); u.y = f2bf(v.y); u.z = f2bf(v.z); u.w = f2bf(v.w);
        *(ushort4*)(xl + e * XLP + k4) = u;
      }
    }
    __syncthreads();

    const u16* rd = hb + ((t & 1) ^ 1) * (32 * HP);
    u16*       wr = hb + (t & 1) * (32 * HP);

    #pragma unroll 1
    for (int half = 0; half < 2; half++){
      f32x4 aR[2][2], aZ[2][2], aNI[2][2], aNH[2][2];
      #pragma unroll
      for (int mt = 0; mt < 2; mt++)
        #pragma unroll
        for (int j = 0; j < 2; j++){
          aR[mt][j] = zero4; aZ[mt][j] = zero4; aNI[mt][j] = zero4; aNH[mt][j] = zero4;
        }

      if (t > 0){
        #pragma unroll
        for (int kt = 0; kt < 8; kt++){
          bf16x8 a0 = *(const bf16x8*)(rd + aoff + kt * 32);
          bf16x8 a1 = *(const bf16x8*)(rd + aoff + 16 * HP + kt * 32);
          #pragma unroll
          for (int j = 0; j < 2; j++){
            const int nt = half * 2 + j;
            const u16* bp = Whh + (size_t)cnt[nt] * 256 + kt * 32 + qoff;
            bf16x8 br = *(const bf16x8*)(bp);
            bf16x8 bz = *(const bf16x8*)(bp + 256 * 256);
            bf16x8 bn = *(const bf16x8*)(bp + 512 * 256);
            aR[0][j]  = MFMA16(a0, br, aR[0][j]);  aR[1][j]  = MFMA16(a1, br, aR[1][j]);
            aZ[0][j]  = MFMA16(a0, bz, aZ[0][j]);  aZ[1][j]  = MFMA16(a1, bz, aZ[1][j]);
            aNH[0][j] = MFMA16(a0, bn, aNH[0][j]); aNH[1][j] = MFMA16(a1, bn, aNH[1][j]);
          }
        }
      }
      #pragma unroll
      for (int kt = 0; kt < DIN / 32; kt++){
        bf16x8 a0 = *(const bf16x8*)(xl + xoff + kt * 32);
        bf16x8 a1 = *(const bf16x8*)(xl + xoff + 16 * XLP + kt * 32);
        #pragma unroll
        for (int j = 0; j < 2; j++){
          const int nt = half * 2 + j;
          const u16* bp = Wih + (size_t)cnt[nt] * DIN + kt * 32 + qoff;
          bf16x8 br = *(const bf16x8*)(bp);
          bf16x8 bz = *(const bf16x8*)(bp + 256 * DIN);
          bf16x8 bn = *(const bf16x8*)(bp + 512 * DIN);
          aR[0][j]  = MFMA16(a0, br, aR[0][j]);  aR[1][j]  = MFMA16(a1, br, aR[1][j]);
          aZ[0][j]  = MFMA16(a0, bz, aZ[0][j]);  aZ[1][j]  = MFMA16(a1, bz, aZ[1][j]);
          aNI[0][j] = MFMA16(a0, bn, aNI[0][j]); aNI[1][j] = MFMA16(a1, bn, aNI[1][j]);
        }
      }
      // gates + h update (double-buffered: no sync needed before write)
      #pragma unroll
      for (int mt = 0; mt < 2; mt++)
        #pragma unroll
        for (int j = 0; j < 2; j++){
          const int nt = half * 2 + j;
          const int c  = cnt[nt];
          #pragma unroll
          for (int q = 0; q < 4; q++){
            const int e = mt * 16 + quad * 4 + q;
            float r = sigmoid_f(aR[mt][j][q] + brc[nt]);
            float z = sigmoid_f(aZ[mt][j][q] + bzc[nt]);
            float n = tanh_f(aNI[mt][j][q] + bnic[nt] + r * (aNH[mt][j][q] + bnhc[nt]));
            float hold = (t > 0) ? bf2f(rd[e * HP + c]) : 0.f;
            float hnew = (1.f - z) * n + z * hold;
            hs[mt][nt][q] += hnew;
            if (t < 7) wr[e * HP + c] = f2bf(hnew);
          }
        }
    }
  }

  __syncthreads();   // all t=7 reads of hb[0] done
  // emb = mean(h) -> hb[0]; stage nodef[src] -> xl
  {
    u16* eb = hb;
    #pragma unroll
    for (int mt = 0; mt < 2; mt++)
      #pragma unroll
      for (int nt = 0; nt < 4; nt++)
        #pragma unroll
        for (int q = 0; q < 4; q++){
          const int e = mt * 16 + quad * 4 + q;
          eb[e * HP + cnt[nt]] = f2bf(hs[mt][nt][q] * 0.125f);
        }
    constexpr int R4 = NFD / 4;
    for (int i = tid; i < 32 * R4; i += 256){
      int e  = i / R4;
      int k4 = (i - e * R4) * 4;
      const float4 v = *(const float4*)(nodef + (size_t)srcs_s[e] * NFD + k4);
      ushort4 u;
      u.x = f2bf(v.x); u.y = f2bf(v.y); u.z = f2bf(v.z); u.w = f2bf(v.w);
      *(ushort4*)(xl + e * XLP + k4) = u;
    }
  }
  __syncthreads();

  // phi GEMM: K = NFD (xl) + 256 (emb in hb[0])
  f32x4 P[2][4];
  #pragma unroll
  for (int mt = 0; mt < 2; mt++)
    #pragma unroll
    for (int nt = 0; nt < 4; nt++) P[mt][nt] = zero4;

  #pragma unroll
  for (int kt = 0; kt < NFD / 32; kt++){
    bf16x8 a0 = *(const bf16x8*)(xl + xoff + kt * 32);
    bf16x8 a1 = *(const bf16x8*)(xl + xoff + 16 * XLP + kt * 32);
    #pragma unroll
    for (int nt = 0; nt < 4; nt++){
      const u16* bp = phiW + (size_t)cnt[nt] * KP + kt * 32 + qoff;
      bf16x8 b = *(const bf16x8*)(bp);
      P[0][nt] = MFMA16(a0, b, P[0][nt]);
      P[1][nt] = MFMA16(a1, b, P[1][nt]);
    }
  }
  #pragma unroll
  for (int kt = 0; kt < 8; kt++){
    bf16x8 a0 = *(const bf16x8*)(hb + aoff + kt * 32);
    bf16x8 a1 = *(const bf16x8*)(hb + aoff + 16 * HP + kt * 32);
    #pragma unroll
    for (int nt = 0; nt < 4; nt++){
      const u16* bp = phiW + (size_t)cnt[nt] * KP + NFD + kt * 32 + qoff;
      bf16x8 b = *(const bf16x8*)(bp);
      P[0][nt] = MFMA16(a0, b, P[0][nt]);
      P[1][nt] = MFMA16(a1, b, P[1][nt]);
    }
  }

  // bias + LN stats via shuffle reduction (LN over 256 cols per edge-row)
  float sl[2][4], sq[2][4];
  #pragma unroll
  for (int mt = 0; mt < 2; mt++)
    #pragma unroll
    for (int q = 0; q < 4; q++){ sl[mt][q] = 0.f; sq[mt][q] = 0.f; }
  #pragma unroll
  for (int mt = 0; mt < 2; mt++)
    #pragma unroll
    for (int nt = 0; nt < 4; nt++)
      #pragma unroll
      for (int q = 0; q < 4; q++){
        float v = P[mt][nt][q] + pb[nt];
        P[mt][nt][q] = v;
        sl[mt][q] += v;
        sq[mt][q] += v * v;
      }
  #pragma unroll
  for (int off = 1; off < 16; off <<= 1){
    #pragma unroll
    for (int mt = 0; mt < 2; mt++)
      #pragma unroll
      for (int q = 0; q < 4; q++){
        sl[mt][q] += __shfl_xor(sl[mt][q], off);
        sq[mt][q] += __shfl_xor(sq[mt][q], off);
      }
  }
  if (ln15 == 0){
    #pragma unroll
    for (int mt = 0; mt < 2; mt++)
      #pragma unroll
      for (int q = 0; q < 4; q++){
        int row = mt * 16 + quad * 4 + q;
        sums_s[wave * 32 + row] = sl[mt][q];
        sqs_s[wave * 32 + row]  = sq[mt][q];
      }
  }
  __syncthreads();
  if (tid < 32){
    float m = 0.f, qq = 0.f;
    #pragma unroll
    for (int w = 0; w < 4; w++){ m += sums_s[w * 32 + tid]; qq += sqs_s[w * 32 + tid]; }
    m  *= (1.f / 256.f);
    qq *= (1.f / 256.f);
    mean_s[tid] = m;
    rstd_s[tid] = rsqrtf(fmaxf(qq - m * m, 0.f) + 1e-5f);
  }
  __syncthreads();

  // y = relu(LN(...)), msg = relu(y - hist[src]) -> atomic scatter into delta[dst]
  #pragma unroll
  for (int mt = 0; mt < 2; mt++)
    #pragma unroll
    for (int nt = 0; nt < 4; nt++){
      const int c = cnt[nt];
      #pragma unroll
      for (int q = 0; q < 4; q++){
        const int e  = mt * 16 + quad * 4 + q;
        const int ge = e0 + e;
        float y = (P[mt][nt][q] - mean_s[e]) * rstd_s[e] * gg[nt] + gb[nt];
        y = fmaxf(y, 0.f);
        float mv = y - hist[(size_t)srcs_s[e] * 256 + c];
        if (ge < E && mv > 0.f)
          atomicAdd(delta + (size_t)dsts_s[e] * 256 + c, mv);
      }
    }
}

// ---------------------------------------------------------------------------
// self-SLNN: out = relu(LN(feat[nid] @ W[:, WS-K:].T + b)); optional
// out2 = out - hist[nid].
// ---------------------------------------------------------------------------
template<int K, int WS>
__global__ __launch_bounds__(256)
void self_slnn_kernel(int N,
    const float* __restrict__ feat,
    const int*   __restrict__ nid,
    const float* __restrict__ W,
    const float* __restrict__ b,
    const float* __restrict__ g,
    const float* __restrict__ beta,
    const float* __restrict__ hist,
    float* __restrict__ out,
    float* __restrict__ out2)
{
  constexpr int R = 8;
  __shared__ float X[R*K];
  __shared__ float O[R*256];
  __shared__ float mean_s[R], rstd_s[R];
  __shared__ int   nids[R];
  const int tid = threadIdx.x;
  const int n0  = blockIdx.x * R;
  if (tid < R) nids[tid] = (n0 + tid < N) ? nid[n0 + tid] : 0;
  __syncthreads();
  for (int i = tid; i < R*K; i += 256){
    int r = i / K, k = i - r*K;
    X[i] = feat[(size_t)nids[r]*K + k];
  }
  __syncthreads();
  const int c = tid;
  const float* Wc = W + (size_t)c*WS + (WS - K);
  float acc[R];
  const float bc0 = b[c];
  #pragma unroll
  for (int r = 0; r < R; r++) acc[r] = bc0;
  #pragma unroll 1
  for (int k = 0; k < K; k += 4){
    float4 w = *(const float4*)(Wc + k);
    #pragma unroll
    for (int r = 0; r < R; r++){
      float4 xv = *(const float4*)(X + r*K + k);
      acc[r] += w.x*xv.x + w.y*xv.y + w.z*xv.z + w.w*xv.w;
    }
  }
  #pragma unroll
  for (int r = 0; r < R; r++) O[r*256 + c] = acc[r];
  __syncthreads();
  ln_stats_rows<R>(O, mean_s, rstd_s);
  __syncthreads();
  const float gc = g[c], bc = beta[c];
  #pragma unroll
  for (int r = 0; r < R; r++){
    int n = n0 + r;
    if (n < N){
      float y = fmaxf((acc[r] - mean_s[r]) * rstd_s[r] * gc + bc, 0.f);
      out[(size_t)n*256 + c] = y;
      if (out2) out2[(size_t)n*256 + c] = y - hist[(size_t)nids[r]*256 + c];
    }
  }
}

// ---------------------------------------------------------------------------
// compose-SLNN: X = [ (delta - selfA)*subg (+ agg*normv) | selfB ]  (K=512)
// ---------------------------------------------------------------------------
__global__ __launch_bounds__(256)
void compose_slnn_kernel(int N,
    const float* __restrict__ delta,
    const float* __restrict__ selfA,
    const float* __restrict__ selfB,
    const float* __restrict__ subg,
    const float* __restrict__ agg,
    const float* __restrict__ normv,
    const float* __restrict__ W,     // [256, 512]
    const float* __restrict__ b,
    const float* __restrict__ g,
    const float* __restrict__ beta,
    float* __restrict__ out)
{
  constexpr int R = 8;
  __shared__ float X[R*512];
  __shared__ float O[R*256];
  __shared__ float mean_s[R], rstd_s[R];
  const int tid = threadIdx.x;
  const int n0  = blockIdx.x * R;
  for (int i = tid; i < R*512; i += 256){
    int r = i >> 9, k = i & 511;
    int n = n0 + r;
    float v = 0.f;
    if (n < N){
      if (k < 256){
        v = (delta[(size_t)n*256 + k] - selfA[(size_t)n*256 + k]) * subg[n];
        if (agg) v += agg[(size_t)n*256 + k] * normv[n];
      } else {
        v = selfB[(size_t)n*256 + (k - 256)];
      }
    }
    X[i] = v;
  }
  __syncthreads();
  const int c = tid;
  const float* Wc = W + (size_t)c*512;
  float acc[R];
  const float bc0 = b[c];
  #pragma unroll
  for (int r = 0; r < R; r++) acc[r] = bc0;
  #pragma unroll 1
  for (int k = 0; k < 512; k += 4){
    float4 w = *(const float4*)(Wc + k);
    #pragma unroll
    for (int r = 0; r < R; r++){
      float4 xv = *(const float4*)(X + r*512 + k);
      acc[r] += w.x*xv.x + w.y*xv.y + w.z*xv.z + w.w*xv.w;
    }
  }
  #pragma unroll
  for (int r = 0; r < R; r++) O[r*256 + c] = acc[r];
  __syncthreads();
  ln_stats_rows<R>(O, mean_s, rstd_s);
  __syncthreads();
  const float gc = g[c], bc = beta[c];
  #pragma unroll
  for (int r = 0; r < R; r++){
    int n = n0 + r;
    if (n < N)
      out[(size_t)n*256 + c] = fmaxf((acc[r] - mean_s[r]) * rstd_s[r] * gc + bc, 0.f);
  }
}

// ---------------------------------------------------------------------------
// readout: logit = (h2 @ fc1.T + b1) @ fc2.T + b2
// ---------------------------------------------------------------------------
__global__ __launch_bounds__(256)
void readout_kernel(int N,
    const float* __restrict__ h2,
    const float* __restrict__ W1,  // [512, 256]
    const float* __restrict__ b1,
    const float* __restrict__ W2,  // [16, 512]
    const float* __restrict__ b2,
    float* __restrict__ out)
{
  constexpr int R = 8;
  __shared__ float X[R*256];
  __shared__ float T[R*512];
  const int tid = threadIdx.x;
  const int n0  = blockIdx.x * R;
  for (int i = tid; i < R*256; i += 256){
    int r = i >> 8, k = i & 255;
    int n = n0 + r;
    X[i] = (n < N) ? h2[(size_t)n*256 + k] : 0.f;
  }
  __syncthreads();
  const int c = tid;
  const float* Wa = W1 + (size_t)c*256;
  const float* Wb = W1 + (size_t)(c+256)*256;
  float acca[R], accb[R];
  const float ba = b1[c], bb = b1[c+256];
  #pragma unroll
  for (int r = 0; r < R; r++){ acca[r] = ba; accb[r] = bb; }
  #pragma unroll 1
  for (int k = 0; k < 256; k += 4){
    float4 wa = *(const float4*)(Wa + k);
    float4 wb = *(const float4*)(Wb + k);
    #pragma unroll
    for (int r = 0; r < R; r++){
      float4 xv = *(const float4*)(X + r*256 + k);
      acca[r] += wa.x*xv.x + wa.y*xv.y + wa.z*xv.z + wa.w*xv.w;
      accb[r] += wb.x*xv.x + wb.y*xv.y + wb.z*xv.z + wb.w*xv.w;
    }
  }
  #pragma unroll
  for (int r = 0; r < R; r++){ T[r*512 + c] = acca[r]; T[r*512 + 256 + c] = accb[r]; }
  __syncthreads();
  if (tid < R*16){
    int r = tid >> 4, o = tid & 15;
    int n = n0 + r;
    if (n < N){
      float s = b2[o];
      const float* w  = W2 + (size_t)o*512;
      const float* tr = T + r*512;
      #pragma unroll 4
      for (int k = 0; k < 512; k++) s += tr[k]*w[k];
      out[(size_t)n*16 + o] = s;
    }
  }
}

// ---------------------------------------------------------------------------
extern "C" void kernel_launch(void* const* d_in, const int* in_sizes, int n_in,
                              void* d_out, int out_size, void* d_ws, size_t ws_size,
                              hipStream_t stream) {
  const float* nf     = (const float*)d_in[0];
  const float* x0     = (const float*)d_in[1];
  const float* x1     = (const float*)d_in[2];
  const float* hist0  = (const float*)d_in[3];
  const float* hist1  = (const float*)d_in[4];
  const float* aggh1  = (const float*)d_in[5];
  const float* subg1  = (const float*)d_in[6];
  const float* subg2  = (const float*)d_in[7];
  const float* norm2  = (const float*)d_in[8];
  const int*   src0   = (const int*)d_in[9];
  const int*   dst0   = (const int*)d_in[10];
  const int*   src1   = (const int*)d_in[11];
  const int*   dst1   = (const int*)d_in[12];
  const int*   nid0   = (const int*)d_in[13];
  const int*   nid1   = (const int*)d_in[14];
  const float* g0Wih  = (const float*)d_in[15];
  const float* g0Whh  = (const float*)d_in[16];
  const float* g0bih  = (const float*)d_in[17];
  const float* g0bhh  = (const float*)d_in[18];
  const float* g1Wih  = (const float*)d_in[19];
  const float* g1Whh  = (const float*)d_in[20];
  const float* g1bih  = (const float*)d_in[21];
  const float* g1bhh  = (const float*)d_in[22];
  const float* phi0W  = (const float*)d_in[23];
  const float* phi0b  = (const float*)d_in[24];
  const float* phi0g  = (const float*)d_in[25];
  const float* phi0be = (const float*)d_in[26];
  const float* phi1W  = (const float*)d_in[27];
  const float* phi1b  = (const float*)d_in[28];
  const float* phi1g  = (const float*)d_in[29];
  const float* phi1be = (const float*)d_in[30];
  const float* nu0W   = (const float*)d_in[31];
  const float* nu0b   = (const float*)d_in[32];
  const float* nu0g   = (const float*)d_in[33];
  const float* nu0be  = (const float*)d_in[34];
  const float* nu1W   = (const float*)d_in[35];
  const float* nu1b   = (const float*)d_in[36];
  const float* nu1g   = (const float*)d_in[37];
  const float* nu1be  = (const float*)d_in[38];
  const float* fc1W   = (const float*)d_in[39];
  const float* fc1b   = (const float*)d_in[40];
  const float* fc2W   = (const float*)d_in[41];
  const float* fc2b   = (const float*)d_in[42];

  const int E0 = in_sizes[9];
  const int E1 = in_sizes[11];
  const int N1 = in_sizes[13];
  const int N2 = in_sizes[14];

  float* ws     = (float*)d_ws;
  float* delta0 = ws;
  float* selfh0 = delta0 + (size_t)N1*256;
  float* h1p    = selfh0 + (size_t)N1*256;
  float* delta1 = h1p    + (size_t)N1*256;
  float* selfh1 = delta1 + (size_t)N2*256;
  float* selfd1 = selfh1 + (size_t)N2*256;
  float* h2p    = selfd1 + (size_t)N2*256;

  // bf16 weight copies (converted every call; ws is re-poisoned by harness)
  u16* wbf       = (u16*)(h2p + (size_t)N2*256);
  u16* g0Wih_bf  = wbf;
  u16* g0Whh_bf  = g0Wih_bf + 768*64;
  u16* phi0W_bf  = g0Whh_bf + 768*256;
  u16* g1Wih_bf  = phi0W_bf + 256*384;
  u16* g1Whh_bf  = g1Wih_bf + 768*256;
  u16* phi1W_bf  = g1Whh_bf + 768*256;

  hipMemsetAsync(delta0, 0, (size_t)N1*256*sizeof(float), stream);
  hipMemsetAsync(delta1, 0, (size_t)N2*256*sizeof(float), stream);

  cvt_bf16_kernel<<<192, 256, 0, stream>>>(g0Wih, g0Wih_bf, 768*64);
  cvt_bf16_kernel<<<768, 256, 0, stream>>>(g0Whh, g0Whh_bf, 768*256);
  cvt_bf16_kernel<<<384, 256, 0, stream>>>(phi0W, phi0W_bf, 256*384);
  cvt_bf16_kernel<<<768, 256, 0, stream>>>(g1Wih, g1Wih_bf, 768*256);
  cvt_bf16_kernel<<<768, 256, 0, stream>>>(g1Whh, g1Whh_bf, 768*256);
  cvt_bf16_kernel<<<512, 256, 0, stream>>>(phi1W, phi1W_bf, 256*512);

  const int gN1 = (N1 + 7) / 8;
  const int gN2 = (N2 + 7) / 8;

  // ---- layer 0 ----
  self_slnn_kernel<128, 384><<<gN1, 256, 0, stream>>>(
      N1, nf, nid0, phi0W, phi0b, phi0g, phi0be, nullptr, selfh0, nullptr);

  gru_mfma_kernel<64, 128><<<(E0 + 31) / 32, 256, 0, stream>>>(
      E0, x0, nf, src0, dst0, hist0,
      g0Wih_bf, g0Whh_bf, g0bih, g0bhh,
      phi0W_bf, phi0b, phi0g, phi0be, delta0);

  compose_slnn_kernel<<<gN1, 256, 0, stream>>>(
      N1, delta0, selfh0, selfh0, subg1, nullptr, nullptr,
      nu0W, nu0b, nu0g, nu0be, h1p);

  // ---- layer 1 ----
  self_slnn_kernel<256, 512><<<gN2, 256, 0, stream>>>(
      N2, h1p, nid1, phi1W, phi1b, phi1g, phi1be, hist1, selfh1, selfd1);

  gru_mfma_kernel<256, 256><<<(E1 + 31) / 32, 256, 0, stream>>>(
      E1, x1, h1p, src1, dst1, hist1,
      g1Wih_bf, g1Whh_bf, g1bih, g1bhh,
      phi1W_bf, phi1b, phi1g, phi1be, delta1);

  compose_slnn_kernel<<<gN2, 256, 0, stream>>>(
      N2, delta1, selfd1, selfh1, subg2, aggh1, norm2,
      nu1W, nu1b, nu1g, nu1be, h2p);

  // ---- readout ----
  readout_kernel<<<gN2, 256, 0, stream>>>(
      N2, h2p, fc1W, fc1b, fc2W, fc2b, (float*)d_out);

  (void)n_in; (void)out_size; (void)ws_size;
}